// Round 13
// baseline (774.545 us; speedup 1.0000x reference)
//
#include <hip/hip_runtime.h>
#include <hip/hip_bf16.h>
#include <cstdint>
#include <cstddef>

// ---------------------------------------------------------------------------
// GCNPool fused pipeline, MI355X/gfx950.  B=8, C=32, N=4000 (pad 4096), T=12.
// Round 13: GEMM prefetch-depth fix.  FIFO audit of round-12 showed A staged
// only 1 phase before its vmcnt wait (~310cyc lead vs ~900cyc HBM) -> ~30%
// stall.  New: A triple-buffered (3x24KB) + B double-paired (2x32KB) = 136KB;
// stage slots per K-tile t: p0=B(t+1)h1, p1=A(t+2), p2=B(t+2)h0; one vmcnt(5)
// per K-tile at p2.  Leads: A=4 phases (>HBM lat), Bh0=3, Bh1=2 (B is the
// L2-resident Abf panel).  Tail uses vmcnt(0) at t>=62.
// ---------------------------------------------------------------------------

typedef __attribute__((ext_vector_type(8))) short s16x8;
typedef __attribute__((ext_vector_type(4))) short s16x4;
typedef __attribute__((ext_vector_type(4))) float f32x4;

#define DEVFN __device__ __forceinline__

DEVFN void gload16(const void* g, void* l) {
  __builtin_amdgcn_global_load_lds((const __attribute__((address_space(1))) unsigned int*)g,
                                   (__attribute__((address_space(3))) unsigned int*)l, 16, 0, 0);
}

DEVFN unsigned short f2bf(float f) {  // round-to-nearest-even f32 -> bf16
  union { float f; unsigned int u; } v; v.f = f;
  unsigned int u = v.u;
  return (unsigned short)((u + 0x7fffu + ((u >> 16) & 1u)) >> 16);
}

// ---------------------------------------------------------------------------
// x (B,C,4000,12) f32 -> Xt[col=b*384+l*32+c][v 4096] bf16  (GEMM1 P operand)
//                     -> Scat slice j=0 (slots 0..3) in l-major k-slot layout
// Scat index: (((l*500 + bn/64)*28 + slot)*64 + bn%64)*8 shorts, bn=b*4000+v.
// ---------------------------------------------------------------------------
__global__ void k_transpose(const float* __restrict__ x,
                            unsigned short* __restrict__ Xt,
                            unsigned short* __restrict__ Scat) {
  __shared__ float ldsT[32 * 417];   // [c]*417 + vv*13 + l
  int v0 = blockIdx.x * 32;
  int b = blockIdx.y;
  int tid = threadIdx.x;
  for (int i = tid; i < 1024; i += 256) {
    int c = i >> 5, vv = i & 31;
    const float* src = x + ((size_t)(b * 32 + c) * 4000 + v0 + vv) * 12;
    f32x4 a0 = *(const f32x4*)(src);
    f32x4 a1 = *(const f32x4*)(src + 4);
    f32x4 a2 = *(const f32x4*)(src + 8);
    float* d = ldsT + c * 417 + vv * 13;
    d[0] = a0.x; d[1] = a0.y; d[2] = a0.z; d[3] = a0.w;
    d[4] = a1.x; d[5] = a1.y; d[6] = a1.z; d[7] = a1.w;
    d[8] = a2.x; d[9] = a2.y; d[10] = a2.z; d[11] = a2.w;
  }
  __syncthreads();
  for (int unit = tid; unit < 384; unit += 256) {
    int l = unit >> 5, c = unit & 31;
    alignas(16) unsigned short tmp[32];
#pragma unroll
    for (int vv = 0; vv < 32; ++vv) tmp[vv] = f2bf(ldsT[c * 417 + vv * 13 + l]);
    unsigned short* dst = Xt + (size_t)(b * 384 + l * 32 + c) * 4096 + v0;
#pragma unroll
    for (int j = 0; j < 4; ++j) *(s16x8*)(dst + j * 8) = *(const s16x8*)(tmp + j * 8);
  }
  for (int unit = tid; unit < 384; unit += 256) {
    int l = unit >> 5, vv = unit & 31;
    alignas(16) unsigned short tmp[32];
#pragma unroll
    for (int c = 0; c < 32; ++c) tmp[c] = f2bf(ldsT[c * 417 + vv * 13 + l]);
    int bn = b * 4000 + v0 + vv;
    unsigned short* dst = Scat + ((((size_t)l * 500 + (bn >> 6)) * 28) * 64 + (bn & 63)) * 8;
#pragma unroll
    for (int j = 0; j < 4; ++j) *(s16x8*)(dst + j * 512) = *(const s16x8*)(tmp + j * 8);
  }
}

// A (4000,4000) f32 -> A_bf[4096][4096] bf16, zero-padded rows/cols.
__global__ void k_castA(const float* __restrict__ A, unsigned short* __restrict__ Abf) {
  int idx = blockIdx.x * 256 + threadIdx.x;
  int r = idx >> 10;
  int c4 = (idx & 1023) << 2;
  alignas(8) unsigned short o[4] = {0, 0, 0, 0};
  if (r < 4000 && c4 < 4000) {
    f32x4 v = *(const f32x4*)(A + (size_t)r * 4000 + c4);
    o[0] = f2bf(v.x); o[1] = f2bf(v.y); o[2] = f2bf(v.z); o[3] = f2bf(v.w);
  }
  *(s16x4*)(Abf + (size_t)r * 4096 + c4) = *(const s16x4*)o;
}

// mlp_w (64,224,1,3) f32 -> Wcat2 per-thread-contiguous:
// [row=(p2*4+g)*16+lr][set s][chunk j=kt*7+ks][8], oc = s*32 + p2*16+lr,
// ic = ks*32+g*8+e.  Size 128*2*21*8 = 43008 shorts = 86KB.
__global__ void k_wcat(const float* __restrict__ mlp_w, unsigned short* __restrict__ Wcat) {
  int i = blockIdx.x * 256 + threadIdx.x;
  if (i >= 43008) return;
  int e = i & 7;
  int j = (i >> 3) % 21;
  int rs = (i >> 3) / 21;
  int s = rs & 1, row = rs >> 1;
  int kt = j / 7, ks = j % 7;
  int p2 = row >> 6, g = (row >> 4) & 3, lr = row & 15;
  int oc = (s ? 32 : 0) + p2 * 16 + lr;
  int ic = ks * 32 + g * 8 + e;
  Wcat[i] = f2bf(mlp_w[((size_t)oc * 224 + ic) * 3 + kt]);
}

// ---------------------------------------------------------------------------
// C[m][n] = sum_k P[m][k] * Q[n][k], bf16, K=4096.  192x256 tile, BK=64,
// 8 waves (2M x 4N, wave-tile 96x64), 3 single-barrier phases per K-tile.
// LDS (shorts): A bufs a=0..2 at a*12288 (192x64 each); B pairs pr=0..1,
// half h at 36864 + (pr*2+h)*8192 (128x64 each).  Total 69632 sh = 136 KiB.
// Stage slots per K-tile t: p0=B(t+1)h1, p1=A(t+2), p2=B(t+2)h0 + vmcnt(5).
// ---------------------------------------------------------------------------
#define MFMA_(a, b, c) __builtin_amdgcn_mfma_f32_16x16x32_bf16(a, b, c, 0, 0, 0)

#define STGA3(ab, t) do {                                                        \
    const unsigned short* _s = aSrc + (size_t)(t) * 64;                          \
    unsigned short* _l = smem + (ab) * 12288;                                    \
    gload16(_s,          _l + tid * 8);                                          \
    gload16(_s + 262144, _l + (512 + tid) * 8);                                  \
    gload16(_s + 524288, _l + (1024 + tid) * 8);                                 \
  } while (0)

#define STGB3(pr, h, t) do {                                                     \
    const unsigned short* _s = bSrc + (size_t)(h) * 524288 + (size_t)(t) * 64;   \
    unsigned short* _l = smem + 36864 + ((pr) * 2 + (h)) * 8192;                 \
    gload16(_s,          _l + tid * 8);                                          \
    gload16(_s + 262144, _l + (512 + tid) * 8);                                  \
  } while (0)

#define LDA3(ab, f, kk) (*(const s16x8*)(smem + (ab) * 12288 + aoff + (f) * 1024 + ((kk) ? sxor : 0)))
#define LDB3(pr, nf, kk) (*(const s16x8*)(smem + 36864 + ((pr) * 2 + hb) * 8192 + boff + (nf) * 1024 + ((kk) ? sxor : 0)))

// single-barrier phase: {reads; stage; [vmcnt]; barrier; lgkm(0); MFMA}
// VM: 0 = none, 1 = vmcnt(5), 2 = vmcnt(0)
#define PHASE3(ab, pr, mp, FIRST, STAGE_CODE, VM) do {                           \
    s16x8 a00 = LDA3(ab, 2 * (mp), 0),     a01 = LDA3(ab, 2 * (mp), 1);          \
    s16x8 a10 = LDA3(ab, 2 * (mp) + 1, 0), a11 = LDA3(ab, 2 * (mp) + 1, 1);      \
    if (FIRST) {                                                                 \
      _Pragma("unroll")                                                          \
      for (int nf = 0; nf < 4; ++nf) { bfr[nf][0] = LDB3(pr, nf, 0); bfr[nf][1] = LDB3(pr, nf, 1); } \
    }                                                                            \
    STAGE_CODE;                                                                  \
    if ((VM) == 1)      asm volatile("s_waitcnt vmcnt(5)" ::: "memory");         \
    else if ((VM) == 2) asm volatile("s_waitcnt vmcnt(0)" ::: "memory");         \
    __builtin_amdgcn_s_barrier();                                                \
    asm volatile("s_waitcnt lgkmcnt(0)" ::: "memory");                           \
    __builtin_amdgcn_s_setprio(1);                                               \
    _Pragma("unroll")                                                            \
    for (int nf = 0; nf < 4; ++nf) {                                             \
      acc[2 * (mp)][nf]     = MFMA_(a00, bfr[nf][0], acc[2 * (mp)][nf]);         \
      acc[2 * (mp)][nf]     = MFMA_(a01, bfr[nf][1], acc[2 * (mp)][nf]);         \
      acc[2 * (mp) + 1][nf] = MFMA_(a10, bfr[nf][0], acc[2 * (mp) + 1][nf]);     \
      acc[2 * (mp) + 1][nf] = MFMA_(a11, bfr[nf][1], acc[2 * (mp) + 1][nf]);     \
    }                                                                            \
    __builtin_amdgcn_s_setprio(0);                                               \
  } while (0)

template <int WRITE_C1>
__global__ __launch_bounds__(512, 2)
void k_gemm(const unsigned short* __restrict__ P, const unsigned short* __restrict__ Q,
            unsigned short* __restrict__ C1, unsigned short* __restrict__ Scat, int jslot) {
  extern __shared__ unsigned short smem[];   // 69632 shorts = 136 KiB
  int tid = threadIdx.x;
  int w = tid >> 6, lane = tid & 63;
  int lr = lane & 15, g = lane >> 4;
  int mq = w >> 2, nq = w & 3;               // 2M x 4N wave grid (96 x 64 each)
  int bid = blockIdx.x;
  int xcd = bid & 7, lid = bid >> 3;         // 256 blocks; per XCD: 2 n-tiles x 16 m-tiles
  int nt = xcd * 2 + (lid >> 4);
  int mt = lid & 15;
  int m0 = mt * 192, n0 = nt * 256;
  int hb = nq >> 1;
  int slot0 = (g ^ (lr & 7)) * 8;
  int sxor = (slot0 & 32) ? -32 : 32;
  int aoff = (mq * 96 + lr) * 64 + slot0;
  int boff = ((nq & 1) * 64 + lr) * 64 + slot0;
  int gk = ((tid & 7) ^ ((tid >> 3) & 7)) * 8;   // pre-swizzled global k offset
  const unsigned short* aSrc = P + (size_t)(m0 + (tid >> 3)) * 4096 + gk;
  const unsigned short* bSrc = Q + (size_t)(n0 + (tid >> 3)) * 4096 + gk;
  f32x4 acc[6][4] = {};
  s16x8 bfr[4][2];

  // prologue (FIFO order matches steady state): A(0), B(0)h0, B(0)h1, A(1),
  // B(1)h0; vmcnt(5) retires A(0)+B(0), keeps A(1)+B(1)h0 in flight.
  STGA3(0, 0);
  STGB3(0, 0, 0);
  STGB3(0, 1, 0);
  STGA3(1, 1);
  STGB3(1, 0, 1);
  asm volatile("s_waitcnt vmcnt(5)" ::: "memory");
  __builtin_amdgcn_s_barrier();

  int a0 = 0;
#pragma unroll 1
  for (int t = 0; t < 64; ++t) {
    int bt = t & 1;
    int a2 = a0 + 2; if (a2 >= 3) a2 -= 3;
    PHASE3(a0, bt, 0, 1, if (t <= 62) STGB3(bt ^ 1, 1, t + 1), 0);
    PHASE3(a0, bt, 1, 0, if (t <= 61) STGA3(a2, t + 2),        0);
    PHASE3(a0, bt, 2, 0, if (t <= 61) STGB3(bt, 0, t + 2),     (t >= 62) ? 2 : 1);
    a0 = (a0 == 2) ? 0 : a0 + 1;
  }

  // epilogue: drain, single-pass repack via LDS [192][264]
  asm volatile("s_waitcnt vmcnt(0) lgkmcnt(0)" ::: "memory");
  __syncthreads();
  unsigned short* eld = smem;
  int rb = g * 4;
#pragma unroll
  for (int f = 0; f < 6; ++f)
#pragma unroll
    for (int nf = 0; nf < 4; ++nf)
#pragma unroll
      for (int r = 0; r < 4; ++r)
        eld[(mq * 96 + f * 16 + rb + r) * 264 + nq * 64 + nf * 16 + lr] = f2bf(acc[f][nf][r]);
  __syncthreads();
  if (WRITE_C1) {
#pragma unroll
    for (int uu = 0; uu < 2; ++uu) {
      int u = uu * 512 + tid;
      if (u < 768) {
        int row = u >> 2, q = u & 3;
        unsigned short* dst = C1 + (size_t)(m0 + row) * 4096 + n0 + q * 64;
        const unsigned short* sp = eld + row * 264 + q * 64;
#pragma unroll
        for (int j = 0; j < 8; ++j) *(s16x8*)(dst + j * 8) = *(const s16x8*)(sp + j * 8);
      }
    }
  }
  int bb2 = m0 / 384, lb = (m0 % 384) >> 5;
#pragma unroll
  for (int uu = 0; uu < 3; ++uu) {
    int u = uu * 512 + tid;                  // 1536 units: 6 lg x 256 nl
    int lg = u >> 8, nl = u & 255;
    int node = n0 + nl;
    if (node < 4000) {
      alignas(16) unsigned short tmp[32];
#pragma unroll
      for (int c = 0; c < 32; ++c) tmp[c] = eld[(lg * 32 + c) * 264 + nl];
      int bn = bb2 * 4000 + node;
      int l2 = lb + lg;
      unsigned short* d2 = Scat + ((((size_t)l2 * 500 + (bn >> 6)) * 28 + jslot) * 64 + (bn & 63)) * 8;
#pragma unroll
      for (int j = 0; j < 4; ++j) *(s16x8*)(d2 + j * 512) = *(const s16x8*)(tmp + j * 8);
    }
  }
}

// ---------------------------------------------------------------------------
// k_mlp v3 + fused ct1: 512 threads (8 waves: p2=w&1 oc-pair-set, bnq=w>>1),
// grid 500 (bn-group of 64).  W hoisted to wa/wb[21] once.  l = 0..11: stage
// slice (contiguous 28KB) into dbuf; rolling acc[3][2]; retire t=l-2 -> gate
// -> accumulate ct1 into g6a[4][6]; write g6 at the end.
// ---------------------------------------------------------------------------
#define MLPSTG(L, BUF) do {                                                    \
    const unsigned short* _sb = Scat + ((size_t)(L) * 500 + grp) * 14336;      \
    unsigned short* _lb = lds + (BUF) * 14336;                                 \
    gload16(_sb + tid * 8,          _lb + tid * 8);                            \
    gload16(_sb + (512 + tid) * 8,  _lb + (512 + tid) * 8);                    \
    gload16(_sb + (1024 + tid) * 8, _lb + (1024 + tid) * 8);                   \
    if (tid < 256) gload16(_sb + (1536 + tid) * 8, _lb + (1536 + tid) * 8);    \
  } while (0)

__global__ __launch_bounds__(512, 2)
void k_mlp(const unsigned short* __restrict__ Wcat, const unsigned short* __restrict__ Scat,
           const float* __restrict__ mlp_b, const float* __restrict__ ct1_w,
           const float* __restrict__ ct1_b, float* __restrict__ g6) {
  __shared__ unsigned short lds[2 * 14336];  // two [28][64][8] S-slices (56KB)
  int tid = threadIdx.x;
  int grp = blockIdx.x;
  int w = tid >> 6, lane = tid & 63;
  int lr = lane & 15, g = lane >> 4;
  int p2 = w & 1, bnq = w >> 1;
  const unsigned short* wrow = Wcat + (size_t)(((p2 * 4 + g) * 16 + lr) * 2) * 168;
  s16x8 wa[21], wb[21];
#pragma unroll
  for (int j = 0; j < 21; ++j) {
    wa[j] = *(const s16x8*)(wrow + j * 8);
    wb[j] = *(const s16x8*)(wrow + 168 + j * 8);
  }
  float mb1[4], mb2[4];
#pragma unroll
  for (int r = 0; r < 4; ++r) {
    mb1[r] = mlp_b[p2 * 16 + g * 4 + r];
    mb2[r] = mlp_b[32 + p2 * 16 + g * 4 + r];
  }
  f32x4 acc[3][2];
  float g6a[4][6] = {};

  MLPSTG(0, 0);
  asm volatile("s_waitcnt vmcnt(0)" ::: "memory");
  __syncthreads();

#pragma unroll
  for (int l = 0; l < 12; ++l) {
    if (l < 11) MLPSTG(l + 1, (l + 1) & 1);
    if (l <= 9) {
      acc[l % 3][0] = (f32x4){0.f, 0.f, 0.f, 0.f};
      acc[l % 3][1] = (f32x4){0.f, 0.f, 0.f, 0.f};
    }
    const unsigned short* sb = lds + (l & 1) * 14336;
#pragma unroll
    for (int kt = 0; kt < 3; ++kt) {
      int t = l - kt;
      if (t < 0 || t > 9) continue;
      int st = t % 3;
#pragma unroll
      for (int ks = 0; ks < 7; ++ks) {
        int j = kt * 7 + ks;
        s16x8 bb = *(const s16x8*)(sb + ((ks * 4 + g) * 64 + bnq * 16 + lr) * 8);
        acc[st][0] = MFMA_(wa[j], bb, acc[st][0]);
        acc[st][1] = MFMA_(wb[j], bb, acc[st][1]);
      }
    }
    if (l >= 2) {                     // retire t = l-2
      int t = l - 2, st = t % 3;
#pragma unroll
      for (int r = 0; r < 4; ++r) {
        float v1 = acc[st][0][r] + mb1[r];
        float v2 = acc[st][1][r] + mb2[r];
        float gg = tanhf(v1) * (1.0f / (1.0f + __expf(-v2)));
#pragma unroll
        for (int q6 = 0; q6 < 6; ++q6) g6a[r][q6] += ct1_w[q6 * 10 + t] * gg;
      }
    }
    asm volatile("s_waitcnt vmcnt(0)" ::: "memory");
    __syncthreads();
  }

  int nglob = grp * 64 + bnq * 16 + lr;
  int b = nglob / 4000, nn = nglob - b * 4000;
#pragma unroll
  for (int r = 0; r < 4; ++r) {
    int c = p2 * 16 + g * 4 + r;
    float* op = g6 + ((size_t)(b * 32 + c) * 4000 + nn) * 6;
#pragma unroll
    for (int q6 = 0; q6 < 6; ++q6) op[q6] = g6a[r][q6] + ct1_b[q6];
  }
}

// f1[b][t][n] = sum_c c1[c] * g6[b][c][n][t]
__global__ void k_f1(const float* __restrict__ g6, const float* __restrict__ c1,
                     float* __restrict__ f1) {
  int idx = blockIdx.x * 128 + threadIdx.x;
  if (idx >= 8 * 4000) return;
  int n = idx % 4000, b = idx / 4000;
  float acc[6] = {};
  const float* gp = g6 + ((size_t)b * 32 * 4000 + n) * 6;
  for (int c = 0; c < 32; ++c) {
    float wv = c1[c];
    const float* p = gp + (size_t)c * 4000 * 6;
#pragma unroll
    for (int t = 0; t < 6; ++t) acc[t] += wv * p[t];
  }
  for (int t = 0; t < 6; ++t) f1[((size_t)b * 6 + t) * 4000 + n] = acc[t];
}

// f2[b][c][t] = sum_n c2[n] * g6[b][c][n][t]
__global__ void k_f2(const float* __restrict__ g6, const float* __restrict__ c2,
                     float* __restrict__ f2) {
  __shared__ float red[256 * 6];
  int bc = blockIdx.x;
  int tid = threadIdx.x;
  float acc[6] = {};
  const float* gp = g6 + (size_t)bc * 4000 * 6;
  for (int n = tid; n < 4000; n += 256) {
    float wv = c2[n];
#pragma unroll
    for (int t = 0; t < 6; ++t) acc[t] += wv * gp[(size_t)n * 6 + t];
  }
  for (int t = 0; t < 6; ++t) red[tid * 6 + t] = acc[t];
  __syncthreads();
  for (int s = 128; s > 0; s >>= 1) {
    if (tid < s)
      for (int t = 0; t < 6; ++t) red[tid * 6 + t] += red[(tid + s) * 6 + t];
    __syncthreads();
  }
  if (tid < 6) f2[bc * 6 + tid] = red[tid];
}

// m1[b][t][c] += sum over n-chunk of f1[b][t][n] * tat_w[n][c]; grid (48,16)
__global__ void k_m1(const float* __restrict__ f1, const float* __restrict__ tw,
                     float* __restrict__ m1) {
  __shared__ float red[8][32];
  int bt = blockIdx.x;
  int nc = blockIdx.y;
  int tid = threadIdx.x;
  int c = tid & 31, gi = tid >> 5;
  float acc = 0.f;
  const float* fp = f1 + (size_t)bt * 4000 + nc * 250;
  const float* twp = tw + ((size_t)nc * 250) * 32 + c;
  for (int n = gi; n < 250; n += 8) acc += fp[n] * twp[n * 32];
  red[gi][c] = acc;
  __syncthreads();
  if (tid < 32) {
    float s = 0.f;
#pragma unroll
    for (int gg = 0; gg < 8; ++gg) s += red[gg][c];
    atomicAdd(&m1[(size_t)bt * 32 + c], s);
  }
}

// logits -> sigmoid -> tat_v mix -> BN1 -> softmax -> coefs[b][t][q]
__global__ void k_att(const float* __restrict__ m1, const float* __restrict__ f2,
                      const float* __restrict__ bias, const float* __restrict__ tv,
                      const float* __restrict__ g1, const float* __restrict__ b1,
                      float* __restrict__ coefs) {
  __shared__ float sig[48 * 6], lgs[48 * 6], mu[6], iv[6];
  int tid = threadIdx.x;
  int b = tid / 6, t = tid % 6;
  if (tid < 48) {
    for (int s = 0; s < 6; ++s) {
      float a = bias[t * 6 + s];
      for (int c = 0; c < 32; ++c)
        a += m1[((size_t)b * 6 + t) * 32 + c] * f2[((size_t)b * 32 + c) * 6 + s];
      sig[tid * 6 + s] = 1.0f / (1.0f + __expf(-a));
    }
  }
  __syncthreads();
  if (tid < 48) {
    for (int q = 0; q < 6; ++q) {
      float a = 0.f;
      for (int s = 0; s < 6; ++s) a += tv[t * 6 + s] * sig[(b * 6 + s) * 6 + q];
      lgs[tid * 6 + q] = a;
    }
  }
  __syncthreads();
  if (tid < 6) {
    float s = 0, s2 = 0;
    for (int r = 0; r < 48; ++r) { float v = lgs[r * 6 + tid]; s += v; s2 += v * v; }
    float m = s / 48.f;
    mu[tid] = m;
    iv[tid] = rsqrtf(s2 / 48.f - m * m + 1e-5f);
  }
  __syncthreads();
  if (tid < 48) {
    float v[6], mx = -1e30f;
    for (int q = 0; q < 6; ++q) {
      v[q] = (lgs[tid * 6 + q] - mu[q]) * iv[q] * g1[q] + b1[q];
      mx = fmaxf(mx, v[q]);
    }
    float s = 0;
    for (int q = 0; q < 6; ++q) { v[q] = __expf(v[q] - mx); s += v[q]; }
    float inv = 1.0f / s;
    for (int q = 0; q < 6; ++q) coefs[tid * 6 + q] = v[q] * inv;
  }
}

// y = attention-mix(g6) + conv1(x)[...,6:] -> out (pre-BN2)
__global__ void k_final1(const float* __restrict__ x, const float* __restrict__ cw,
                         const float* __restrict__ cb, const float* __restrict__ g6,
                         const float* __restrict__ coefs, float* __restrict__ out) {
  __shared__ float xt[32 * 8 * 6];
  __shared__ float cwT[1024];
  __shared__ float cfs[36], cbs[32];
  int n0 = blockIdx.x * 8;
  int b = blockIdx.y;
  int tid = threadIdx.x;
  {
    int ci = tid >> 3, seg = tid & 7;
    const float* xp = x + ((size_t)(b * 32 + ci) * 4000 + n0 + seg) * 12 + 6;
#pragma unroll
    for (int q = 0; q < 6; ++q) xt[(ci * 8 + seg) * 6 + q] = xp[q];
  }
  for (int i = tid; i < 1024; i += 256) { int o = i >> 5, ci = i & 31; cwT[ci * 32 + o] = cw[i]; }
  if (tid < 36) cfs[tid] = coefs[b * 36 + tid];
  if (tid < 32) cbs[tid] = cb[tid];
  __syncthreads();
  int nn = tid & 7, c = tid >> 3;
  const float* gp = g6 + ((size_t)(b * 32 + c) * 4000 + n0 + nn) * 6;
  float gv[6];
#pragma unroll
  for (int l = 0; l < 6; ++l) gv[l] = gp[l];
  float y[6];
#pragma unroll
  for (int q = 0; q < 6; ++q) {
    float at = 0.f;
#pragma unroll
    for (int l = 0; l < 6; ++l) at += gv[l] * cfs[q * 6 + l];
    y[q] = at + cbs[c];
  }
  for (int ci = 0; ci < 32; ++ci) {
    float wv = cwT[ci * 32 + c];
#pragma unroll
    for (int q = 0; q < 6; ++q) y[q] += wv * xt[(ci * 8 + nn) * 6 + q];
  }
  float* op = out + ((size_t)(b * 32 + c) * 4000 + n0 + nn) * 6;
#pragma unroll
  for (int q = 0; q < 6; ++q) op[q] = y[q];
}

// per-channel sum/sumsq of out: grid (4, 256), f32x4 + shfl reduce + atomicAdd
__global__ void k_stats(const float* __restrict__ out, float* __restrict__ stats) {
  __shared__ float r1[4], r2[4];
  int bc = blockIdx.y;
  int c = bc & 31;
  int tid = threadIdx.x;
  const float* p = out + (size_t)bc * 24000 + blockIdx.x * 6000;
  float s = 0.f, s2 = 0.f;
  for (int i = tid * 4; i < 6000; i += 1024) {
    f32x4 v = *(const f32x4*)(p + i);
    s  += v.x + v.y + v.z + v.w;
    s2 += v.x * v.x + v.y * v.y + v.z * v.z + v.w * v.w;
  }
#pragma unroll
  for (int off = 32; off > 0; off >>= 1) {
    s  += __shfl_down(s, off);
    s2 += __shfl_down(s2, off);
  }
  int lane = tid & 63, w = tid >> 6;
  if (lane == 0) { r1[w] = s; r2[w] = s2; }
  __syncthreads();
  if (tid == 0) {
    atomicAdd(&stats[c],      r1[0] + r1[1] + r1[2] + r1[3]);
    atomicAdd(&stats[32 + c], r2[0] + r2[1] + r2[2] + r2[3]);
  }
}

__global__ void k_final2(float* __restrict__ out, const float* __restrict__ stats,
                         const float* __restrict__ g2, const float* __restrict__ b2) {
  int idx = (blockIdx.x * 256 + threadIdx.x) * 4;
  if (idx >= 6144000) return;
  int c = (idx / 24000) % 32;
  float mean = stats[c] * (1.0f / 192000.f);
  float var = stats[32 + c] * (1.0f / 192000.f) - mean * mean;
  float sc = rsqrtf(var + 1e-5f) * g2[c];
  float sh = b2[c] - mean * sc;
  f32x4 v = *(f32x4*)(out + idx);
  v.x = v.x * sc + sh; v.y = v.y * sc + sh; v.z = v.z * sc + sh; v.w = v.w * sc + sh;
  *(f32x4*)(out + idx) = v;
}

// ---------------------------------------------------------------------------
extern "C" void kernel_launch(void* const* d_in, const int* in_sizes, int n_in,
                              void* d_out, int out_size, void* d_ws, size_t ws_size,
                              hipStream_t stream) {
  (void)in_sizes; (void)n_in; (void)out_size;
  const float* x       = (const float*)d_in[0];
  const float* A[3]    = {(const float*)d_in[1], (const float*)d_in[2], (const float*)d_in[3]};
  const float* conv1_w = (const float*)d_in[4];
  const float* conv1_b = (const float*)d_in[5];
  const float* mlp_w   = (const float*)d_in[6];
  const float* mlp_b   = (const float*)d_in[7];
  const float* ct1_w   = (const float*)d_in[8];
  const float* ct1_b   = (const float*)d_in[9];
  const float* c1w     = (const float*)d_in[10];
  const float* c2w     = (const float*)d_in[11];
  const float* tw      = (const float*)d_in[12];
  const float* tbias   = (const float*)d_in[13];
  const float* tv      = (const float*)d_in[14];
  const float* bn1g    = (const float*)d_in[15];
  const float* bn1b    = (const float*)d_in[16];
  const float* bn2g    = (const float*)d_in[17];
  const float* bn2b    = (const float*)d_in[18];
  float* out = (float*)d_out;

  char* ws = (char*)d_ws;
  size_t off = 0;
  auto alloc = [&](size_t bytes) { size_t r = off; off += (bytes + 255) & ~(size_t)255; return r; };
  size_t oScat = alloc(172032000);   // [12][500][28][64][8] bf16
  size_t oXt   = alloc(25165824);    // [3072][4096] bf16 ; later g6 (24.576MB f32)
  size_t oA    = alloc(33554432);    // Abf [4096][4096] bf16
  size_t oY1t  = alloc(25165824);    // [3072][4096] bf16
  size_t oWcat = alloc(86016);
  size_t oF1 = alloc(768000);
  size_t oF2 = alloc(6144);
  size_t oM1 = alloc(6144);
  size_t oCf = alloc(1152);
  size_t oSt = alloc(256);
  if (ws_size < off) return;  // insufficient scratch -> visible validation failure

  unsigned short* Scat = (unsigned short*)(ws + oScat);
  unsigned short* Xt   = (unsigned short*)(ws + oXt);
  float*          g6   = (float*)(ws + oXt);
  unsigned short* Abf  = (unsigned short*)(ws + oA);
  unsigned short* Y1t  = (unsigned short*)(ws + oY1t);
  unsigned short* Wcat = (unsigned short*)(ws + oWcat);

  hipFuncSetAttribute((const void*)k_gemm<0>, hipFuncAttributeMaxDynamicSharedMemorySize, 139264);
  hipFuncSetAttribute((const void*)k_gemm<1>, hipFuncAttributeMaxDynamicSharedMemorySize, 139264);

  hipMemsetAsync(Xt, 0, 25165824, stream);       // v-padding 4000..4095 must be 0
  hipMemsetAsync(ws + oSt, 0, 256, stream);      // stats accumulators
  hipMemsetAsync(ws + oM1, 0, 6144, stream);     // m1 accumulators
  k_transpose<<<dim3(125, 8), 256, 0, stream>>>(x, Xt, Scat);
  k_wcat<<<168, 256, 0, stream>>>(mlp_w, Wcat);
  for (int i = 0; i < 3; ++i) {
    k_castA<<<16384, 256, 0, stream>>>(A[i], Abf);
    // Y1t[col][node] = sum_v Xt[col][v]*Abf[node][v]; Scat slots (2i+1)*4..
    k_gemm<1><<<256, 512, 139264, stream>>>(Xt, Abf, Y1t, Scat, (2 * i + 1) * 4);
    // x2^T[col][node] = sum_v Y1t[col][v]*Abf[node][v]; Scat slots (2i+2)*4..
    k_gemm<0><<<256, 512, 139264, stream>>>(Y1t, Abf, nullptr, Scat, (2 * i + 2) * 4);
  }
  k_mlp<<<500, 512, 0, stream>>>(Wcat, Scat, mlp_b, ct1_w, ct1_b, g6);
  k_f1<<<250, 128, 0, stream>>>(g6, c1w, (float*)(ws + oF1));
  k_f2<<<256, 256, 0, stream>>>(g6, c2w, (float*)(ws + oF2));
  k_m1<<<dim3(48, 16), 256, 0, stream>>>((float*)(ws + oF1), tw, (float*)(ws + oM1));
  k_att<<<1, 64, 0, stream>>>((float*)(ws + oM1), (float*)(ws + oF2), tbias, tv, bn1g, bn1b,
                              (float*)(ws + oCf));
  k_final1<<<dim3(500, 8), 256, 0, stream>>>(x, conv1_w, conv1_b, g6, (float*)(ws + oCf), out);
  k_stats<<<dim3(4, 256), 256, 0, stream>>>(out, (float*)(ws + oSt));
  k_final2<<<6000, 256, 0, stream>>>(out, (float*)(ws + oSt), bn2g, bn2b);
}

// Round 14
// 739.814 us; speedup vs baseline: 1.0469x; 1.0469x over previous
//
#include <hip/hip_runtime.h>
#include <hip/hip_bf16.h>
#include <cstdint>
#include <cstddef>

// ---------------------------------------------------------------------------
// GCNPool fused pipeline, MI355X/gfx950.  B=8, C=32, N=4000 (pad 4096), T=12.
// Round 14: round-13's 3-deep-A schedule with STATIC buffer indices.  R13
// regressed because a0/bt were loop-carried -> every LDS base runtime-
// computed (VALU +2pts, MfmaUtil -3pts).  The (a0,bt) state has period 6:
// unroll the main loop over 6 K-tiles (t=0..59) + explicit 4-tile tail.
// All ds_read/global_load_lds offsets now immediates.  vmcnt(5) per tile
// (A lead = 4 phases > HBM latency), vmcnt(0) at t=62.
// ---------------------------------------------------------------------------

typedef __attribute__((ext_vector_type(8))) short s16x8;
typedef __attribute__((ext_vector_type(4))) short s16x4;
typedef __attribute__((ext_vector_type(4))) float f32x4;

#define DEVFN __device__ __forceinline__

DEVFN void gload16(const void* g, void* l) {
  __builtin_amdgcn_global_load_lds((const __attribute__((address_space(1))) unsigned int*)g,
                                   (__attribute__((address_space(3))) unsigned int*)l, 16, 0, 0);
}

DEVFN unsigned short f2bf(float f) {  // round-to-nearest-even f32 -> bf16
  union { float f; unsigned int u; } v; v.f = f;
  unsigned int u = v.u;
  return (unsigned short)((u + 0x7fffu + ((u >> 16) & 1u)) >> 16);
}

// ---------------------------------------------------------------------------
// x (B,C,4000,12) f32 -> Xt[col=b*384+l*32+c][v 4096] bf16  (GEMM1 P operand)
//                     -> Scat slice j=0 (slots 0..3) in l-major k-slot layout
// Scat index: (((l*500 + bn/64)*28 + slot)*64 + bn%64)*8 shorts, bn=b*4000+v.
// ---------------------------------------------------------------------------
__global__ void k_transpose(const float* __restrict__ x,
                            unsigned short* __restrict__ Xt,
                            unsigned short* __restrict__ Scat) {
  __shared__ float ldsT[32 * 417];   // [c]*417 + vv*13 + l
  int v0 = blockIdx.x * 32;
  int b = blockIdx.y;
  int tid = threadIdx.x;
  for (int i = tid; i < 1024; i += 256) {
    int c = i >> 5, vv = i & 31;
    const float* src = x + ((size_t)(b * 32 + c) * 4000 + v0 + vv) * 12;
    f32x4 a0 = *(const f32x4*)(src);
    f32x4 a1 = *(const f32x4*)(src + 4);
    f32x4 a2 = *(const f32x4*)(src + 8);
    float* d = ldsT + c * 417 + vv * 13;
    d[0] = a0.x; d[1] = a0.y; d[2] = a0.z; d[3] = a0.w;
    d[4] = a1.x; d[5] = a1.y; d[6] = a1.z; d[7] = a1.w;
    d[8] = a2.x; d[9] = a2.y; d[10] = a2.z; d[11] = a2.w;
  }
  __syncthreads();
  for (int unit = tid; unit < 384; unit += 256) {
    int l = unit >> 5, c = unit & 31;
    alignas(16) unsigned short tmp[32];
#pragma unroll
    for (int vv = 0; vv < 32; ++vv) tmp[vv] = f2bf(ldsT[c * 417 + vv * 13 + l]);
    unsigned short* dst = Xt + (size_t)(b * 384 + l * 32 + c) * 4096 + v0;
#pragma unroll
    for (int j = 0; j < 4; ++j) *(s16x8*)(dst + j * 8) = *(const s16x8*)(tmp + j * 8);
  }
  for (int unit = tid; unit < 384; unit += 256) {
    int l = unit >> 5, vv = unit & 31;
    alignas(16) unsigned short tmp[32];
#pragma unroll
    for (int c = 0; c < 32; ++c) tmp[c] = f2bf(ldsT[c * 417 + vv * 13 + l]);
    int bn = b * 4000 + v0 + vv;
    unsigned short* dst = Scat + ((((size_t)l * 500 + (bn >> 6)) * 28) * 64 + (bn & 63)) * 8;
#pragma unroll
    for (int j = 0; j < 4; ++j) *(s16x8*)(dst + j * 512) = *(const s16x8*)(tmp + j * 8);
  }
}

// A (4000,4000) f32 -> A_bf[4096][4096] bf16, zero-padded rows/cols.
__global__ void k_castA(const float* __restrict__ A, unsigned short* __restrict__ Abf) {
  int idx = blockIdx.x * 256 + threadIdx.x;
  int r = idx >> 10;
  int c4 = (idx & 1023) << 2;
  alignas(8) unsigned short o[4] = {0, 0, 0, 0};
  if (r < 4000 && c4 < 4000) {
    f32x4 v = *(const f32x4*)(A + (size_t)r * 4000 + c4);
    o[0] = f2bf(v.x); o[1] = f2bf(v.y); o[2] = f2bf(v.z); o[3] = f2bf(v.w);
  }
  *(s16x4*)(Abf + (size_t)r * 4096 + c4) = *(const s16x4*)o;
}

// mlp_w (64,224,1,3) f32 -> Wcat2 per-thread-contiguous:
// [row=(p2*4+g)*16+lr][set s][chunk j=kt*7+ks][8], oc = s*32 + p2*16+lr,
// ic = ks*32+g*8+e.  Size 128*2*21*8 = 43008 shorts = 86KB.
__global__ void k_wcat(const float* __restrict__ mlp_w, unsigned short* __restrict__ Wcat) {
  int i = blockIdx.x * 256 + threadIdx.x;
  if (i >= 43008) return;
  int e = i & 7;
  int j = (i >> 3) % 21;
  int rs = (i >> 3) / 21;
  int s = rs & 1, row = rs >> 1;
  int kt = j / 7, ks = j % 7;
  int p2 = row >> 6, g = (row >> 4) & 3, lr = row & 15;
  int oc = (s ? 32 : 0) + p2 * 16 + lr;
  int ic = ks * 32 + g * 8 + e;
  Wcat[i] = f2bf(mlp_w[((size_t)oc * 224 + ic) * 3 + kt]);
}

// ---------------------------------------------------------------------------
// C[m][n] = sum_k P[m][k] * Q[n][k], bf16, K=4096.  192x256 tile, BK=64,
// 8 waves (2M x 4N, wave-tile 96x64), 3 single-barrier phases per K-tile.
// LDS (shorts): A bufs a=0..2 at a*12288 (192x64 each); B pairs pr=0..1,
// half h at 36864 + (pr*2+h)*8192 (128x64 each).  Total 69632 sh = 136 KiB.
// Per K-tile t (a0=t%3, bt=t%2): p0 stages B(bt^1,h1,t+1); p1 stages
// A((t+2)%3, t+2); p2 stages B(bt,h0,t+2) + vmcnt(5).  All indices STATIC
// via 6-tile unroll.  FIFO: vmcnt(5) drains exactly tile t+1's 7 loads.
// ---------------------------------------------------------------------------
#define MFMA_(a, b, c) __builtin_amdgcn_mfma_f32_16x16x32_bf16(a, b, c, 0, 0, 0)

#define STGA3(ab, t) do {                                                        \
    const unsigned short* _s = aSrc + (size_t)(t) * 64;                          \
    unsigned short* _l = smem + (ab) * 12288;                                    \
    gload16(_s,          _l + tid * 8);                                          \
    gload16(_s + 262144, _l + (512 + tid) * 8);                                  \
    gload16(_s + 524288, _l + (1024 + tid) * 8);                                 \
  } while (0)

#define STGB3(pr, h, t) do {                                                     \
    const unsigned short* _s = bSrc + (size_t)(h) * 524288 + (size_t)(t) * 64;   \
    unsigned short* _l = smem + 36864 + ((pr) * 2 + (h)) * 8192;                 \
    gload16(_s,          _l + tid * 8);                                          \
    gload16(_s + 262144, _l + (512 + tid) * 8);                                  \
  } while (0)

#define LDA3(ab, f, kk) (*(const s16x8*)(smem + (ab) * 12288 + aoff + (f) * 1024 + ((kk) ? sxor : 0)))
#define LDB3(pr, nf, kk) (*(const s16x8*)(smem + 36864 + ((pr) * 2 + hb) * 8192 + boff + (nf) * 1024 + ((kk) ? sxor : 0)))

// single-barrier phase: {reads; stage; [vmcnt]; barrier; lgkm(0); MFMA}
// VM: 0 = none, 1 = vmcnt(5), 2 = vmcnt(0)
#define PHASE3(ab, pr, mp, FIRST, STAGE_CODE, VM) do {                           \
    s16x8 a00 = LDA3(ab, 2 * (mp), 0),     a01 = LDA3(ab, 2 * (mp), 1);          \
    s16x8 a10 = LDA3(ab, 2 * (mp) + 1, 0), a11 = LDA3(ab, 2 * (mp) + 1, 1);      \
    if (FIRST) {                                                                 \
      _Pragma("unroll")                                                          \
      for (int nf = 0; nf < 4; ++nf) { bfr[nf][0] = LDB3(pr, nf, 0); bfr[nf][1] = LDB3(pr, nf, 1); } \
    }                                                                            \
    STAGE_CODE;                                                                  \
    if ((VM) == 1)      asm volatile("s_waitcnt vmcnt(5)" ::: "memory");         \
    else if ((VM) == 2) asm volatile("s_waitcnt vmcnt(0)" ::: "memory");         \
    __builtin_amdgcn_s_barrier();                                                \
    asm volatile("s_waitcnt lgkmcnt(0)" ::: "memory");                           \
    __builtin_amdgcn_s_setprio(1);                                               \
    _Pragma("unroll")                                                            \
    for (int nf = 0; nf < 4; ++nf) {                                             \
      acc[2 * (mp)][nf]     = MFMA_(a00, bfr[nf][0], acc[2 * (mp)][nf]);         \
      acc[2 * (mp)][nf]     = MFMA_(a01, bfr[nf][1], acc[2 * (mp)][nf]);         \
      acc[2 * (mp) + 1][nf] = MFMA_(a10, bfr[nf][0], acc[2 * (mp) + 1][nf]);     \
      acc[2 * (mp) + 1][nf] = MFMA_(a11, bfr[nf][1], acc[2 * (mp) + 1][nf]);     \
    }                                                                            \
    __builtin_amdgcn_s_setprio(0);                                               \
  } while (0)

// one K-tile = 3 phases; S0/S1/S2 are the stage ops, VM2 the p2 wait code
#define TILE3(A0, BT, S0, S1, S2, VM2) do {                                      \
    PHASE3(A0, BT, 0, 1, S0, 0);                                                 \
    PHASE3(A0, BT, 1, 0, S1, 0);                                                 \
    PHASE3(A0, BT, 2, 0, S2, VM2);                                               \
  } while (0)

template <int WRITE_C1>
__global__ __launch_bounds__(512, 2)
void k_gemm(const unsigned short* __restrict__ P, const unsigned short* __restrict__ Q,
            unsigned short* __restrict__ C1, unsigned short* __restrict__ Scat, int jslot) {
  extern __shared__ unsigned short smem[];   // 69632 shorts = 136 KiB
  int tid = threadIdx.x;
  int w = tid >> 6, lane = tid & 63;
  int lr = lane & 15, g = lane >> 4;
  int mq = w >> 2, nq = w & 3;               // 2M x 4N wave grid (96 x 64 each)
  int bid = blockIdx.x;
  int xcd = bid & 7, lid = bid >> 3;         // 256 blocks; per XCD: 2 n-tiles x 16 m-tiles
  int nt = xcd * 2 + (lid >> 4);
  int mt = lid & 15;
  int m0 = mt * 192, n0 = nt * 256;
  int hb = nq >> 1;
  int slot0 = (g ^ (lr & 7)) * 8;
  int sxor = (slot0 & 32) ? -32 : 32;
  int aoff = (mq * 96 + lr) * 64 + slot0;
  int boff = ((nq & 1) * 64 + lr) * 64 + slot0;
  int gk = ((tid & 7) ^ ((tid >> 3) & 7)) * 8;   // pre-swizzled global k offset
  const unsigned short* aSrc = P + (size_t)(m0 + (tid >> 3)) * 4096 + gk;
  const unsigned short* bSrc = Q + (size_t)(n0 + (tid >> 3)) * 4096 + gk;
  f32x4 acc[6][4] = {};
  s16x8 bfr[4][2];

  // prologue (FIFO order matches steady state): A(0), B(0)h0, B(0)h1, A(1),
  // B(1)h0; vmcnt(5) retires A(0)+B(0), keeps A(1)+B(1)h0 in flight.
  STGA3(0, 0);
  STGB3(0, 0, 0);
  STGB3(0, 1, 0);
  STGA3(1, 1);
  STGB3(1, 0, 1);
  asm volatile("s_waitcnt vmcnt(5)" ::: "memory");
  __builtin_amdgcn_s_barrier();

  // main loop: 10 groups of 6 K-tiles, all buffer indices static
#pragma unroll 1
  for (int tb = 0; tb < 60; tb += 6) {
    TILE3(0, 0, STGB3(1, 1, tb + 1), STGA3(2, tb + 2), STGB3(0, 0, tb + 2), 1);
    TILE3(1, 1, STGB3(0, 1, tb + 2), STGA3(0, tb + 3), STGB3(1, 0, tb + 3), 1);
    TILE3(2, 0, STGB3(1, 1, tb + 3), STGA3(1, tb + 4), STGB3(0, 0, tb + 4), 1);
    TILE3(0, 1, STGB3(0, 1, tb + 4), STGA3(2, tb + 5), STGB3(1, 0, tb + 5), 1);
    TILE3(1, 0, STGB3(1, 1, tb + 5), STGA3(0, tb + 6), STGB3(0, 0, tb + 6), 1);
    TILE3(2, 1, STGB3(0, 1, tb + 6), STGA3(1, tb + 7), STGB3(1, 0, tb + 7), 1);
  }
  // tail: t = 60..63
  TILE3(0, 0, STGB3(1, 1, 61), STGA3(2, 62), STGB3(0, 0, 62), 1);
  TILE3(1, 1, STGB3(0, 1, 62), STGA3(0, 63), STGB3(1, 0, 63), 1);
  TILE3(2, 0, STGB3(1, 1, 63), (void)0,      (void)0,          2);
  TILE3(0, 1, (void)0,         (void)0,      (void)0,          0);

  // epilogue: drain, single-pass repack via LDS [192][264]
  asm volatile("s_waitcnt vmcnt(0) lgkmcnt(0)" ::: "memory");
  __syncthreads();
  unsigned short* eld = smem;
  int rb = g * 4;
#pragma unroll
  for (int f = 0; f < 6; ++f)
#pragma unroll
    for (int nf = 0; nf < 4; ++nf)
#pragma unroll
      for (int r = 0; r < 4; ++r)
        eld[(mq * 96 + f * 16 + rb + r) * 264 + nq * 64 + nf * 16 + lr] = f2bf(acc[f][nf][r]);
  __syncthreads();
  if (WRITE_C1) {
#pragma unroll
    for (int uu = 0; uu < 2; ++uu) {
      int u = uu * 512 + tid;
      if (u < 768) {
        int row = u >> 2, q = u & 3;
        unsigned short* dst = C1 + (size_t)(m0 + row) * 4096 + n0 + q * 64;
        const unsigned short* sp = eld + row * 264 + q * 64;
#pragma unroll
        for (int j = 0; j < 8; ++j) *(s16x8*)(dst + j * 8) = *(const s16x8*)(sp + j * 8);
      }
    }
  }
  int bb2 = m0 / 384, lb = (m0 % 384) >> 5;
#pragma unroll
  for (int uu = 0; uu < 3; ++uu) {
    int u = uu * 512 + tid;                  // 1536 units: 6 lg x 256 nl
    int lg = u >> 8, nl = u & 255;
    int node = n0 + nl;
    if (node < 4000) {
      alignas(16) unsigned short tmp[32];
#pragma unroll
      for (int c = 0; c < 32; ++c) tmp[c] = eld[(lg * 32 + c) * 264 + nl];
      int bn = bb2 * 4000 + node;
      int l2 = lb + lg;
      unsigned short* d2 = Scat + ((((size_t)l2 * 500 + (bn >> 6)) * 28 + jslot) * 64 + (bn & 63)) * 8;
#pragma unroll
      for (int j = 0; j < 4; ++j) *(s16x8*)(d2 + j * 512) = *(const s16x8*)(tmp + j * 8);
    }
  }
}

// ---------------------------------------------------------------------------
// k_mlp v3 + fused ct1: 512 threads (8 waves: p2=w&1 oc-pair-set, bnq=w>>1),
// grid 500 (bn-group of 64).  W hoisted to wa/wb[21] once.  l = 0..11: stage
// slice (contiguous 28KB) into dbuf; rolling acc[3][2]; retire t=l-2 -> gate
// -> accumulate ct1 into g6a[4][6]; write g6 at the end.
// ---------------------------------------------------------------------------
#define MLPSTG(L, BUF) do {                                                    \
    const unsigned short* _sb = Scat + ((size_t)(L) * 500 + grp) * 14336;      \
    unsigned short* _lb = lds + (BUF) * 14336;                                 \
    gload16(_sb + tid * 8,          _lb + tid * 8);                            \
    gload16(_sb + (512 + tid) * 8,  _lb + (512 + tid) * 8);                    \
    gload16(_sb + (1024 + tid) * 8, _lb + (1024 + tid) * 8);                   \
    if (tid < 256) gload16(_sb + (1536 + tid) * 8, _lb + (1536 + tid) * 8);    \
  } while (0)

__global__ __launch_bounds__(512, 2)
void k_mlp(const unsigned short* __restrict__ Wcat, const unsigned short* __restrict__ Scat,
           const float* __restrict__ mlp_b, const float* __restrict__ ct1_w,
           const float* __restrict__ ct1_b, float* __restrict__ g6) {
  __shared__ unsigned short lds[2 * 14336];  // two [28][64][8] S-slices (56KB)
  int tid = threadIdx.x;
  int grp = blockIdx.x;
  int w = tid >> 6, lane = tid & 63;
  int lr = lane & 15, g = lane >> 4;
  int p2 = w & 1, bnq = w >> 1;
  const unsigned short* wrow = Wcat + (size_t)(((p2 * 4 + g) * 16 + lr) * 2) * 168;
  s16x8 wa[21], wb[21];
#pragma unroll
  for (int j = 0; j < 21; ++j) {
    wa[j] = *(const s16x8*)(wrow + j * 8);
    wb[j] = *(const s16x8*)(wrow + 168 + j * 8);
  }
  float mb1[4], mb2[4];
#pragma unroll
  for (int r = 0; r < 4; ++r) {
    mb1[r] = mlp_b[p2 * 16 + g * 4 + r];
    mb2[r] = mlp_b[32 + p2 * 16 + g * 4 + r];
  }
  f32x4 acc[3][2];
  float g6a[4][6] = {};

  MLPSTG(0, 0);
  asm volatile("s_waitcnt vmcnt(0)" ::: "memory");
  __syncthreads();

#pragma unroll
  for (int l = 0; l < 12; ++l) {
    if (l < 11) MLPSTG(l + 1, (l + 1) & 1);
    if (l <= 9) {
      acc[l % 3][0] = (f32x4){0.f, 0.f, 0.f, 0.f};
      acc[l % 3][1] = (f32x4){0.f, 0.f, 0.f, 0.f};
    }
    const unsigned short* sb = lds + (l & 1) * 14336;
#pragma unroll
    for (int kt = 0; kt < 3; ++kt) {
      int t = l - kt;
      if (t < 0 || t > 9) continue;
      int st = t % 3;
#pragma unroll
      for (int ks = 0; ks < 7; ++ks) {
        int j = kt * 7 + ks;
        s16x8 bb = *(const s16x8*)(sb + ((ks * 4 + g) * 64 + bnq * 16 + lr) * 8);
        acc[st][0] = MFMA_(wa[j], bb, acc[st][0]);
        acc[st][1] = MFMA_(wb[j], bb, acc[st][1]);
      }
    }
    if (l >= 2) {                     // retire t = l-2
      int t = l - 2, st = t % 3;
#pragma unroll
      for (int r = 0; r < 4; ++r) {
        float v1 = acc[st][0][r] + mb1[r];
        float v2 = acc[st][1][r] + mb2[r];
        float gg = tanhf(v1) * (1.0f / (1.0f + __expf(-v2)));
#pragma unroll
        for (int q6 = 0; q6 < 6; ++q6) g6a[r][q6] += ct1_w[q6 * 10 + t] * gg;
      }
    }
    asm volatile("s_waitcnt vmcnt(0)" ::: "memory");
    __syncthreads();
  }

  int nglob = grp * 64 + bnq * 16 + lr;
  int b = nglob / 4000, nn = nglob - b * 4000;
#pragma unroll
  for (int r = 0; r < 4; ++r) {
    int c = p2 * 16 + g * 4 + r;
    float* op = g6 + ((size_t)(b * 32 + c) * 4000 + nn) * 6;
#pragma unroll
    for (int q6 = 0; q6 < 6; ++q6) op[q6] = g6a[r][q6] + ct1_b[q6];
  }
}

// f1[b][t][n] = sum_c c1[c] * g6[b][c][n][t]
__global__ void k_f1(const float* __restrict__ g6, const float* __restrict__ c1,
                     float* __restrict__ f1) {
  int idx = blockIdx.x * 128 + threadIdx.x;
  if (idx >= 8 * 4000) return;
  int n = idx % 4000, b = idx / 4000;
  float acc[6] = {};
  const float* gp = g6 + ((size_t)b * 32 * 4000 + n) * 6;
  for (int c = 0; c < 32; ++c) {
    float wv = c1[c];
    const float* p = gp + (size_t)c * 4000 * 6;
#pragma unroll
    for (int t = 0; t < 6; ++t) acc[t] += wv * p[t];
  }
  for (int t = 0; t < 6; ++t) f1[((size_t)b * 6 + t) * 4000 + n] = acc[t];
}

// f2[b][c][t] = sum_n c2[n] * g6[b][c][n][t]
__global__ void k_f2(const float* __restrict__ g6, const float* __restrict__ c2,
                     float* __restrict__ f2) {
  __shared__ float red[256 * 6];
  int bc = blockIdx.x;
  int tid = threadIdx.x;
  float acc[6] = {};
  const float* gp = g6 + (size_t)bc * 4000 * 6;
  for (int n = tid; n < 4000; n += 256) {
    float wv = c2[n];
#pragma unroll
    for (int t = 0; t < 6; ++t) acc[t] += wv * gp[(size_t)n * 6 + t];
  }
  for (int t = 0; t < 6; ++t) red[tid * 6 + t] = acc[t];
  __syncthreads();
  for (int s = 128; s > 0; s >>= 1) {
    if (tid < s)
      for (int t = 0; t < 6; ++t) red[tid * 6 + t] += red[(tid + s) * 6 + t];
    __syncthreads();
  }
  if (tid < 6) f2[bc * 6 + tid] = red[tid];
}

// m1[b][t][c] += sum over n-chunk of f1[b][t][n] * tat_w[n][c]; grid (48,16)
__global__ void k_m1(const float* __restrict__ f1, const float* __restrict__ tw,
                     float* __restrict__ m1) {
  __shared__ float red[8][32];
  int bt = blockIdx.x;
  int nc = blockIdx.y;
  int tid = threadIdx.x;
  int c = tid & 31, gi = tid >> 5;
  float acc = 0.f;
  const float* fp = f1 + (size_t)bt * 4000 + nc * 250;
  const float* twp = tw + ((size_t)nc * 250) * 32 + c;
  for (int n = gi; n < 250; n += 8) acc += fp[n] * twp[n * 32];
  red[gi][c] = acc;
  __syncthreads();
  if (tid < 32) {
    float s = 0.f;
#pragma unroll
    for (int gg = 0; gg < 8; ++gg) s += red[gg][c];
    atomicAdd(&m1[(size_t)bt * 32 + c], s);
  }
}

// logits -> sigmoid -> tat_v mix -> BN1 -> softmax -> coefs[b][t][q]
__global__ void k_att(const float* __restrict__ m1, const float* __restrict__ f2,
                      const float* __restrict__ bias, const float* __restrict__ tv,
                      const float* __restrict__ g1, const float* __restrict__ b1,
                      float* __restrict__ coefs) {
  __shared__ float sig[48 * 6], lgs[48 * 6], mu[6], iv[6];
  int tid = threadIdx.x;
  int b = tid / 6, t = tid % 6;
  if (tid < 48) {
    for (int s = 0; s < 6; ++s) {
      float a = bias[t * 6 + s];
      for (int c = 0; c < 32; ++c)
        a += m1[((size_t)b * 6 + t) * 32 + c] * f2[((size_t)b * 32 + c) * 6 + s];
      sig[tid * 6 + s] = 1.0f / (1.0f + __expf(-a));
    }
  }
  __syncthreads();
  if (tid < 48) {
    for (int q = 0; q < 6; ++q) {
      float a = 0.f;
      for (int s = 0; s < 6; ++s) a += tv[t * 6 + s] * sig[(b * 6 + s) * 6 + q];
      lgs[tid * 6 + q] = a;
    }
  }
  __syncthreads();
  if (tid < 6) {
    float s = 0, s2 = 0;
    for (int r = 0; r < 48; ++r) { float v = lgs[r * 6 + tid]; s += v; s2 += v * v; }
    float m = s / 48.f;
    mu[tid] = m;
    iv[tid] = rsqrtf(s2 / 48.f - m * m + 1e-5f);
  }
  __syncthreads();
  if (tid < 48) {
    float v[6], mx = -1e30f;
    for (int q = 0; q < 6; ++q) {
      v[q] = (lgs[tid * 6 + q] - mu[q]) * iv[q] * g1[q] + b1[q];
      mx = fmaxf(mx, v[q]);
    }
    float s = 0;
    for (int q = 0; q < 6; ++q) { v[q] = __expf(v[q] - mx); s += v[q]; }
    float inv = 1.0f / s;
    for (int q = 0; q < 6; ++q) coefs[tid * 6 + q] = v[q] * inv;
  }
}

// y = attention-mix(g6) + conv1(x)[...,6:] -> out (pre-BN2)
__global__ void k_final1(const float* __restrict__ x, const float* __restrict__ cw,
                         const float* __restrict__ cb, const float* __restrict__ g6,
                         const float* __restrict__ coefs, float* __restrict__ out) {
  __shared__ float xt[32 * 8 * 6];
  __shared__ float cwT[1024];
  __shared__ float cfs[36], cbs[32];
  int n0 = blockIdx.x * 8;
  int b = blockIdx.y;
  int tid = threadIdx.x;
  {
    int ci = tid >> 3, seg = tid & 7;
    const float* xp = x + ((size_t)(b * 32 + ci) * 4000 + n0 + seg) * 12 + 6;
#pragma unroll
    for (int q = 0; q < 6; ++q) xt[(ci * 8 + seg) * 6 + q] = xp[q];
  }
  for (int i = tid; i < 1024; i += 256) { int o = i >> 5, ci = i & 31; cwT[ci * 32 + o] = cw[i]; }
  if (tid < 36) cfs[tid] = coefs[b * 36 + tid];
  if (tid < 32) cbs[tid] = cb[tid];
  __syncthreads();
  int nn = tid & 7, c = tid >> 3;
  const float* gp = g6 + ((size_t)(b * 32 + c) * 4000 + n0 + nn) * 6;
  float gv[6];
#pragma unroll
  for (int l = 0; l < 6; ++l) gv[l] = gp[l];
  float y[6];
#pragma unroll
  for (int q = 0; q < 6; ++q) {
    float at = 0.f;
#pragma unroll
    for (int l = 0; l < 6; ++l) at += gv[l] * cfs[q * 6 + l];
    y[q] = at + cbs[c];
  }
  for (int ci = 0; ci < 32; ++ci) {
    float wv = cwT[ci * 32 + c];
#pragma unroll
    for (int q = 0; q < 6; ++q) y[q] += wv * xt[(ci * 8 + nn) * 6 + q];
  }
  float* op = out + ((size_t)(b * 32 + c) * 4000 + n0 + nn) * 6;
#pragma unroll
  for (int q = 0; q < 6; ++q) op[q] = y[q];
}

// per-channel sum/sumsq of out: grid (4, 256), f32x4 + shfl reduce + atomicAdd
__global__ void k_stats(const float* __restrict__ out, float* __restrict__ stats) {
  __shared__ float r1[4], r2[4];
  int bc = blockIdx.y;
  int c = bc & 31;
  int tid = threadIdx.x;
  const float* p = out + (size_t)bc * 24000 + blockIdx.x * 6000;
  float s = 0.f, s2 = 0.f;
  for (int i = tid * 4; i < 6000; i += 1024) {
    f32x4 v = *(const f32x4*)(p + i);
    s  += v.x + v.y + v.z + v.w;
    s2 += v.x * v.x + v.y * v.y + v.z * v.z + v.w * v.w;
  }
#pragma unroll
  for (int off = 32; off > 0; off >>= 1) {
    s  += __shfl_down(s, off);
    s2 += __shfl_down(s2, off);
  }
  int lane = tid & 63, w = tid >> 6;
  if (lane == 0) { r1[w] = s; r2[w] = s2; }
  __syncthreads();
  if (tid == 0) {
    atomicAdd(&stats[c],      r1[0] + r1[1] + r1[2] + r1[3]);
    atomicAdd(&stats[32 + c], r2[0] + r2[1] + r2[2] + r2[3]);
  }
}

__global__ void k_final2(float* __restrict__ out, const float* __restrict__ stats,
                         const float* __restrict__ g2, const float* __restrict__ b2) {
  int idx = (blockIdx.x * 256 + threadIdx.x) * 4;
  if (idx >= 6144000) return;
  int c = (idx / 24000) % 32;
  float mean = stats[c] * (1.0f / 192000.f);
  float var = stats[32 + c] * (1.0f / 192000.f) - mean * mean;
  float sc = rsqrtf(var + 1e-5f) * g2[c];
  float sh = b2[c] - mean * sc;
  f32x4 v = *(f32x4*)(out + idx);
  v.x = v.x * sc + sh; v.y = v.y * sc + sh; v.z = v.z * sc + sh; v.w = v.w * sc + sh;
  *(f32x4*)(out + idx) = v;
}

// ---------------------------------------------------------------------------
extern "C" void kernel_launch(void* const* d_in, const int* in_sizes, int n_in,
                              void* d_out, int out_size, void* d_ws, size_t ws_size,
                              hipStream_t stream) {
  (void)in_sizes; (void)n_in; (void)out_size;
  const float* x       = (const float*)d_in[0];
  const float* A[3]    = {(const float*)d_in[1], (const float*)d_in[2], (const float*)d_in[3]};
  const float* conv1_w = (const float*)d_in[4];
  const float* conv1_b = (const float*)d_in[5];
  const float* mlp_w   = (const float*)d_in[6];
  const float* mlp_b   = (const float*)d_in[7];
  const float* ct1_w   = (const float*)d_in[8];
  const float* ct1_b   = (const float*)d_in[9];
  const float* c1w     = (const float*)d_in[10];
  const float* c2w     = (const float*)d_in[11];
  const float* tw      = (const float*)d_in[12];
  const float* tbias   = (const float*)d_in[13];
  const float* tv      = (const float*)d_in[14];
  const float* bn1g    = (const float*)d_in[15];
  const float* bn1b    = (const float*)d_in[16];
  const float* bn2g    = (const float*)d_in[17];
  const float* bn2b    = (const float*)d_in[18];
  float* out = (float*)d_out;

  char* ws = (char*)d_ws;
  size_t off = 0;
  auto alloc = [&](size_t bytes) { size_t r = off; off += (bytes + 255) & ~(size_t)255; return r; };
  size_t oScat = alloc(172032000);   // [12][500][28][64][8] bf16
  size_t oXt   = alloc(25165824);    // [3072][4096] bf16 ; later g6 (24.576MB f32)
  size_t oA    = alloc(33554432);    // Abf [4096][4096] bf16
  size_t oY1t  = alloc(25165824);    // [3072][4096] bf16
  size_t oWcat = alloc(86016);
  size_t oF1 = alloc(768000);
  size_t oF2 = alloc(6144);
  size_t oM1 = alloc(6144);
  size_t oCf = alloc(1152);
  size_t oSt = alloc(256);
  if (ws_size < off) return;  // insufficient scratch -> visible validation failure

  unsigned short* Scat = (unsigned short*)(ws + oScat);
  unsigned short* Xt   = (unsigned short*)(ws + oXt);
  float*          g6   = (float*)(ws + oXt);
  unsigned short* Abf  = (unsigned short*)(ws + oA);
  unsigned short* Y1t  = (unsigned short*)(ws + oY1t);
  unsigned short* Wcat = (unsigned short*)(ws + oWcat);

  hipFuncSetAttribute((const void*)k_gemm<0>, hipFuncAttributeMaxDynamicSharedMemorySize, 139264);
  hipFuncSetAttribute((const void*)k_gemm<1>, hipFuncAttributeMaxDynamicSharedMemorySize, 139264);

  hipMemsetAsync(Xt, 0, 25165824, stream);       // v-padding 4000..4095 must be 0
  hipMemsetAsync(ws + oSt, 0, 256, stream);      // stats accumulators
  hipMemsetAsync(ws + oM1, 0, 6144, stream);     // m1 accumulators
  k_transpose<<<dim3(125, 8), 256, 0, stream>>>(x, Xt, Scat);
  k_wcat<<<168, 256, 0, stream>>>(mlp_w, Wcat);
  for (int i = 0; i < 3; ++i) {
    k_castA<<<16384, 256, 0, stream>>>(A[i], Abf);
    // Y1t[col][node] = sum_v Xt[col][v]*Abf[node][v]; Scat slots (2i+1)*4..
    k_gemm<1><<<256, 512, 139264, stream>>>(Xt, Abf, Y1t, Scat, (2 * i + 1) * 4);
    // x2^T[col][node] = sum_v Y1t[col][v]*Abf[node][v]; Scat slots (2i+2)*4..
    k_gemm<0><<<256, 512, 139264, stream>>>(Y1t, Abf, nullptr, Scat, (2 * i + 2) * 4);
  }
  k_mlp<<<500, 512, 0, stream>>>(Wcat, Scat, mlp_b, ct1_w, ct1_b, g6);
  k_f1<<<250, 128, 0, stream>>>(g6, c1w, (float*)(ws + oF1));
  k_f2<<<256, 256, 0, stream>>>(g6, c2w, (float*)(ws + oF2));
  k_m1<<<dim3(48, 16), 256, 0, stream>>>((float*)(ws + oF1), tw, (float*)(ws + oM1));
  k_att<<<1, 64, 0, stream>>>((float*)(ws + oM1), (float*)(ws + oF2), tbias, tv, bn1g, bn1b,
                              (float*)(ws + oCf));
  k_final1<<<dim3(500, 8), 256, 0, stream>>>(x, conv1_w, conv1_b, g6, (float*)(ws + oCf), out);
  k_stats<<<dim3(4, 256), 256, 0, stream>>>(out, (float*)(ws + oSt));
  k_final2<<<6000, 256, 0, stream>>>(out, (float*)(ws + oSt), bn2g, bn2b);
}